// Round 4
// baseline (1419.417 us; speedup 1.0000x reference)
//
#include <hip/hip_runtime.h>
#include <cstdint>
#include <cstddef>

#define ALPHA 0.2f

__device__ __forceinline__ float lrelu(float x) { return x > 0.f ? x : ALPHA * x; }

// round-to-nearest-even bf16 quantization, kept in f32
__device__ __forceinline__ float qbf(float x)
{
    uint32_t u = __float_as_uint(x);
    uint32_t r = (u + 0x7FFFu + ((u >> 16) & 1u)) & 0xFFFF0000u;
    return __uint_as_float(r);
}

// ---------------------------------------------------------------------------
// GEMM1: H[n, h*64+o] = sum_k q(x[n,k]) * q(Wh[h,k,o])   (f32 accum)
// Tile 64 rows x 256 cols, BK=32, 256 threads, micro 4x16.
// ---------------------------------------------------------------------------
__global__ __launch_bounds__(256) void k_gemm1(const float* __restrict__ x,
                                               const float* __restrict__ Wh,
                                               float* __restrict__ H, int n)
{
    __shared__ float As[32][68];    // transposed A tile, padded
    __shared__ float Bs[32][256];
    const int tid = threadIdx.x;
    const int row0 = blockIdx.x * 64;
    const int tx = tid & 15, ty = tid >> 4;

    float acc[4][16];
#pragma unroll
    for (int r = 0; r < 4; ++r)
#pragma unroll
        for (int c = 0; c < 16; ++c) acc[r][c] = 0.f;

    for (int k0 = 0; k0 < 256; k0 += 32) {
        for (int j = tid; j < 512; j += 256) {
            int r = j >> 3, kk = (j & 7) << 2;
            int gr = row0 + r; if (gr >= n) gr = n - 1;
            const float4 v = *(const float4*)&x[(size_t)gr * 256 + k0 + kk];
            As[kk + 0][r] = qbf(v.x); As[kk + 1][r] = qbf(v.y);
            As[kk + 2][r] = qbf(v.z); As[kk + 3][r] = qbf(v.w);
        }
        for (int j = tid; j < 2048; j += 256) {
            int kk = j >> 6, c4 = j & 63;
            int h = c4 >> 4, o = (c4 & 15) << 2;
            const float4 v = *(const float4*)&Wh[h * 16384 + (k0 + kk) * 64 + o];
            float* bp = &Bs[kk][c4 << 2];
            bp[0] = qbf(v.x); bp[1] = qbf(v.y); bp[2] = qbf(v.z); bp[3] = qbf(v.w);
        }
        __syncthreads();
#pragma unroll
        for (int kk = 0; kk < 32; ++kk) {
            const float4 a  = *(const float4*)&As[kk][ty << 2];
            const float4 b0 = *(const float4*)&Bs[kk][tx * 16 + 0];
            const float4 b1 = *(const float4*)&Bs[kk][tx * 16 + 4];
            const float4 b2 = *(const float4*)&Bs[kk][tx * 16 + 8];
            const float4 b3 = *(const float4*)&Bs[kk][tx * 16 + 12];
            const float av[4]  = {a.x, a.y, a.z, a.w};
            const float bv[16] = {b0.x, b0.y, b0.z, b0.w, b1.x, b1.y, b1.z, b1.w,
                                  b2.x, b2.y, b2.z, b2.w, b3.x, b3.y, b3.z, b3.w};
#pragma unroll
            for (int r = 0; r < 4; ++r)
#pragma unroll
                for (int c = 0; c < 16; ++c) acc[r][c] += av[r] * bv[c];
        }
        __syncthreads();
    }
#pragma unroll
    for (int r = 0; r < 4; ++r) {
        int gr = row0 + (ty << 2) + r;
        if (gr < n) {
            float* dst = &H[(size_t)gr * 256 + tx * 16];
#pragma unroll
            for (int i = 0; i < 4; ++i)
                *(float4*)&dst[4 * i] = make_float4(acc[r][4 * i + 0], acc[r][4 * i + 1],
                                                    acc[r][4 * i + 2], acc[r][4 * i + 3]);
        }
    }
}

// ---------------------------------------------------------------------------
// scores1: s1src[n,h] = sum_o H[n,h*64+o]*q(a[h,o]); s1dst with q(a[h,64+o]).
// ---------------------------------------------------------------------------
__global__ __launch_bounds__(256) void k_scores1(const float* __restrict__ H,
                                                 const float* __restrict__ a,
                                                 float* __restrict__ s1src,
                                                 float* __restrict__ s1dst, int n)
{
    int gtid = blockIdx.x * 256 + threadIdx.x;
    int node = gtid >> 6, lane = gtid & 63;
    if (node >= n) return;
    int h = lane >> 4, o0 = (lane & 15) << 2;
    const float4 hv = *(const float4*)&H[(size_t)node * 256 + lane * 4];
    float as0 = qbf(a[h * 128 + o0 + 0]), as1 = qbf(a[h * 128 + o0 + 1]);
    float as2 = qbf(a[h * 128 + o0 + 2]), as3 = qbf(a[h * 128 + o0 + 3]);
    float ad0 = qbf(a[h * 128 + 64 + o0 + 0]), ad1 = qbf(a[h * 128 + 64 + o0 + 1]);
    float ad2 = qbf(a[h * 128 + 64 + o0 + 2]), ad3 = qbf(a[h * 128 + 64 + o0 + 3]);
    float ps = hv.x * as0 + hv.y * as1 + hv.z * as2 + hv.w * as3;
    float pd = hv.x * ad0 + hv.y * ad1 + hv.z * ad2 + hv.w * ad3;
#pragma unroll
    for (int m = 8; m >= 1; m >>= 1) {
        ps += __shfl_xor(ps, m);
        pd += __shfl_xor(pd, m);
    }
    if ((lane & 15) == 0) {
        s1src[node * 4 + h] = ps;
        s1dst[node * 4 + h] = pd;
    }
}

// ---------------------------------------------------------------------------
// CSR build (scatter stores EDGE IDs; sorted per bucket afterwards)
// ---------------------------------------------------------------------------
__global__ void k_zero(int* __restrict__ p, int n)
{
    int i = blockIdx.x * 256 + threadIdx.x;
    if (i < n) p[i] = 0;
}

__global__ void k_hist(const int* __restrict__ src, int* __restrict__ counts, int e)
{
    int i = blockIdx.x * 256 + threadIdx.x;
    if (i < e) atomicAdd(&counts[src[i]], 1);
}

__global__ __launch_bounds__(256) void k_blocksum(const int* __restrict__ counts,
                                                  int* __restrict__ bsum, int n)
{
    int tid = threadIdx.x;
    int i0 = blockIdx.x * 2048 + tid * 8;
    int s = 0;
#pragma unroll
    for (int k = 0; k < 8; ++k) {
        int i = i0 + k;
        if (i < n) s += counts[i];
    }
#pragma unroll
    for (int m = 32; m >= 1; m >>= 1) s += __shfl_xor(s, m);
    __shared__ int ws[4];
    int lane = tid & 63, wv = tid >> 6;
    if (lane == 0) ws[wv] = s;
    __syncthreads();
    if (tid == 0) bsum[blockIdx.x] = ws[0] + ws[1] + ws[2] + ws[3];
}

__global__ void k_scanmeta(const int* __restrict__ bsum, int* __restrict__ choff, int nchunk)
{
    int lane = threadIdx.x;   // 64 threads, nchunk <= 64
    int v = (lane < nchunk) ? bsum[lane] : 0;
    int incl = v;
#pragma unroll
    for (int d = 1; d < 64; d <<= 1) {
        int t = __shfl_up(incl, d);
        if (lane >= d) incl += t;
    }
    if (lane < nchunk) choff[lane] = incl - v;
}

__global__ __launch_bounds__(256) void k_apply(const int* __restrict__ counts,
                                               const int* __restrict__ choff,
                                               int* __restrict__ offsets,
                                               int* __restrict__ cursor, int n)
{
    int tid = threadIdx.x;
    int i0 = blockIdx.x * 2048 + tid * 8;
    int c[8]; int s = 0;
#pragma unroll
    for (int k = 0; k < 8; ++k) {
        int i = i0 + k;
        c[k] = (i < n) ? counts[i] : 0;
        s += c[k];
    }
    int lane = tid & 63, wv = tid >> 6;
    int incl = s;
#pragma unroll
    for (int d = 1; d < 64; d <<= 1) {
        int t = __shfl_up(incl, d);
        if (lane >= d) incl += t;
    }
    __shared__ int ws[4];
    if (lane == 63) ws[wv] = incl;
    __syncthreads();
    int woff = 0;
    for (int w = 0; w < 4; ++w)
        if (w < wv) woff += ws[w];
    int run = incl - s + woff + choff[blockIdx.x];
#pragma unroll
    for (int k = 0; k < 8; ++k) {
        int i = i0 + k;
        if (i < n) { offsets[i] = run; cursor[i] = run; }
        run += c[k];
        if (i == n - 1) offsets[n] = run;
    }
}

__global__ void k_scatter(const int* __restrict__ src,
                          int* __restrict__ cursor, int* __restrict__ csr, int e)
{
    int i = blockIdx.x * 256 + threadIdx.x;
    if (i < e) {
        int pos = atomicAdd(&cursor[src[i]], 1);
        csr[pos] = i;                    // store edge id (unique key)
    }
}

// sort each bucket by edge id (deterministic; == np's edge-index order),
// then replace edge ids with dst node ids.
__global__ __launch_bounds__(256) void k_sortcsr(const int* __restrict__ dst_in,
                                                 const int* __restrict__ offsets,
                                                 int* __restrict__ csr, int n)
{
    int gtid = blockIdx.x * 256 + threadIdx.x;
    int node = gtid >> 6, lane = gtid & 63;
    if (node >= n) return;
    int beg = offsets[node], end = offsets[node + 1];
    int cnt = end - beg;
    if (cnt <= 0) return;
    if (cnt <= 64) {
        int v = (lane < cnt) ? csr[beg + lane] : 0x7FFFFFFF;
        // 64-wide bitonic sort (ascending)
#pragma unroll
        for (int k = 2; k <= 64; k <<= 1) {
#pragma unroll
            for (int j = k >> 1; j > 0; j >>= 1) {
                int o = __shfl_xor(v, j);
                bool up    = ((lane & k) == 0);
                bool lower = ((lane & j) == 0);
                int mn = min(v, o), mx = max(v, o);
                v = (lower == up) ? mn : mx;
            }
        }
        if (lane < cnt) csr[beg + lane] = dst_in[v];
    } else {
        // cold path (degree > 64): lane 0 insertion sort, then convert
        if (lane == 0) {
            for (int i = beg + 1; i < end; ++i) {
                int key = csr[i]; int j = i - 1;
                while (j >= beg && csr[j] > key) { csr[j + 1] = csr[j]; --j; }
                csr[j + 1] = key;
            }
        }
        __threadfence();
        for (int i = lane; i < cnt; i += 64) {
            int eid = csr[beg + i];
            csr[beg + i] = dst_in[eid];
        }
    }
}

// ---------------------------------------------------------------------------
// agg1 (fused with GEMM2): per-node wave; strictly sequential edge order.
// x1 fragment -> h2 = x1 @ q(Wout), s2 scores; x1 never materialized.
// ---------------------------------------------------------------------------
__global__ __launch_bounds__(256) void k_agg1(const int* __restrict__ csr_dst,
                                              const int* __restrict__ offsets,
                                              const float* __restrict__ H,
                                              const float* __restrict__ s1src,
                                              const float* __restrict__ s1dst,
                                              const float* __restrict__ Wout,
                                              const float* __restrict__ aout,
                                              float* __restrict__ h2,
                                              float* __restrict__ s2src,
                                              float* __restrict__ s2dst, int n)
{
    __shared__ float Wt[32][256];   // Wt[c][k] = q(Wout[k,c])
    const int tid = threadIdx.x;
    for (int j = tid; j < 8192; j += 256) {
        int k = j >> 5, c = j & 31;
        Wt[c][k] = qbf(Wout[j]);
    }
    __syncthreads();

    int gtid = blockIdx.x * 256 + tid;
    int node = gtid >> 6, lane = gtid & 63;
    if (node >= n) return;
    int h = lane >> 4;
    int beg = offsets[node], end = offsets[node + 1];
    float ssrc = s1src[node * 4 + h];
    float ax = 0.f, ay = 0.f, az = 0.f, aw = 0.f, wsum = 0.f;
    for (int j = beg; j < end; j += 64) {
        int dvec = (j + lane < end) ? csr_dst[j + lane] : 0;
        int cnt = min(64, end - j);
        for (int t = 0; t < cnt; ++t) {
            int d = __shfl(dvec, t);
            float sd = s1dst[d * 4 + h];
            float w = expf(-lrelu(ssrc + sd));
            const float4 hv = *(const float4*)&H[(size_t)d * 256 + lane * 4];
            ax += w * hv.x; ay += w * hv.y;
            az += w * hv.z; aw += w * hv.w;
            wsum += w;
        }
    }
    float inv = 1.f / wsum;
    float r0 = ax * inv, r1 = ay * inv, r2 = az * inv, r3 = aw * inv;
    r0 = r0 > 0.f ? r0 : expm1f(r0);   // elu -> x1 cols 4L..4L+3
    r1 = r1 > 0.f ? r1 : expm1f(r1);
    r2 = r2 > 0.f ? r2 : expm1f(r2);
    r3 = r3 > 0.f ? r3 : expm1f(r3);

    // fused GEMM2: partial h2[c] over this lane's 4 k's, wave tree-reduce
    float p[32];
#pragma unroll
    for (int c = 0; c < 32; ++c) {
        const float4 wv = *(const float4*)&Wt[c][lane << 2];
        p[c] = r0 * wv.x + r1 * wv.y + r2 * wv.z + r3 * wv.w;
    }
#pragma unroll
    for (int m = 32; m >= 1; m >>= 1) {
#pragma unroll
        for (int c = 0; c < 32; ++c) p[c] += __shfl_xor(p[c], m);
    }
    if (lane == 0) {
        float ss = 0.f, sd2 = 0.f;
#pragma unroll
        for (int c = 0; c < 32; ++c) {
            ss  += p[c] * qbf(aout[c]);
            sd2 += p[c] * qbf(aout[32 + c]);
        }
        float* dst = &h2[(size_t)node * 32];
#pragma unroll
        for (int i = 0; i < 8; ++i)
            *(float4*)&dst[4 * i] = make_float4(p[4 * i + 0], p[4 * i + 1],
                                                p[4 * i + 2], p[4 * i + 3]);
        s2src[node] = ss;
        s2dst[node] = sd2;
    }
}

// ---------------------------------------------------------------------------
// agg2 + elu + log_softmax -> out. One wave per node; lane = class (dup x2);
// strictly sequential edge order.
// ---------------------------------------------------------------------------
__global__ __launch_bounds__(256) void k_agg2(const int* __restrict__ csr_dst,
                                              const int* __restrict__ offsets,
                                              const float* __restrict__ h2,
                                              const float* __restrict__ s2src,
                                              const float* __restrict__ s2dst,
                                              float* __restrict__ out, int n)
{
    int gtid = blockIdx.x * 256 + threadIdx.x;
    int node = gtid >> 6, lane = gtid & 63;
    if (node >= n) return;
    int c = lane & 31;
    int beg = offsets[node], end = offsets[node + 1];
    float ssrc = s2src[node];
    float acc = 0.f, wsum = 0.f;
    for (int j = beg; j < end; j += 64) {
        int dvec = (j + lane < end) ? csr_dst[j + lane] : 0;
        int cnt = min(64, end - j);
        for (int t = 0; t < cnt; ++t) {
            int d = __shfl(dvec, t);
            float sd = s2dst[d];
            float w = expf(-lrelu(ssrc + sd));
            acc += w * h2[(size_t)d * 32 + c];
            wsum += w;
        }
    }
    float v = acc / wsum;
    v = v > 0.f ? v : expm1f(v);          // elu
    float m = v;
#pragma unroll
    for (int i = 16; i >= 1; i >>= 1) m = fmaxf(m, __shfl_xor(m, i));
    float ex = expf(v - m);
    float se = ex;
#pragma unroll
    for (int i = 16; i >= 1; i >>= 1) se += __shfl_xor(se, i);
    float r = v - m - logf(se);
    if (lane < 32) out[(size_t)node * 32 + c] = r;
}

// ---------------------------------------------------------------------------
extern "C" void kernel_launch(void* const* d_in, const int* in_sizes, int n_in,
                              void* d_out, int out_size, void* d_ws, size_t ws_size,
                              hipStream_t stream)
{
    const float* x    = (const float*)d_in[0];
    const int*   ei   = (const int*)d_in[1];
    const float* Wh   = (const float*)d_in[2];
    const float* ah   = (const float*)d_in[3];
    const float* Wout = (const float*)d_in[4];
    const float* aout = (const float*)d_in[5];
    float* out = (float*)d_out;

    const int n = in_sizes[0] / 256;
    const int e = in_sizes[1] / 2;
    const int* src = ei;
    const int* dst = ei + e;

    auto align = [](size_t v) { return (v + 255) & ~(size_t)255; };
    char* w = (char*)d_ws;
    float* H      = (float*)w; w += align((size_t)n * 256 * 4);   // 102.4 MB
    float* h2     = (float*)w; w += align((size_t)n * 32 * 4);    //  12.8 MB
    int*   csr    = (int*)w;   w += align((size_t)e * 4);         //   6.4 MB
    float* s1src  = (float*)w; w += align((size_t)n * 4 * 4);
    float* s1dst  = (float*)w; w += align((size_t)n * 4 * 4);
    int*   counts = (int*)w;   w += align((size_t)n * 4);
    int*   offs   = (int*)w;   w += align((size_t)(n + 1) * 4);
    int*   cursor = (int*)w;   w += align((size_t)n * 4);
    float* s2src  = (float*)w; w += align((size_t)n * 4);
    float* s2dst  = (float*)w; w += align((size_t)n * 4);
    int*   bsum   = (int*)w;   w += align(4096);
    int*   choff  = (int*)w;   w += align(4096);

    const int nchunk = (n + 2047) / 2048;
    const int gN256  = (n + 255) / 256;
    const int gWave  = (n + 3) / 4;      // 4 node-waves per 256-thread block
    const int gE     = (e + 255) / 256;

    // layer 1 feature transform (inputs bf16-quantized on load)
    k_gemm1<<<(n + 63) / 64, 256, 0, stream>>>(x, Wh, H, n);
    k_scores1<<<gWave, 256, 0, stream>>>(H, ah, s1src, s1dst, n);

    // deterministic CSR by src (sorted buckets)
    k_zero<<<gN256, 256, 0, stream>>>(counts, n);
    k_hist<<<gE, 256, 0, stream>>>(src, counts, e);
    k_blocksum<<<nchunk, 256, 0, stream>>>(counts, bsum, n);
    k_scanmeta<<<1, 64, 0, stream>>>(bsum, choff, nchunk);
    k_apply<<<nchunk, 256, 0, stream>>>(counts, choff, offs, cursor, n);
    k_scatter<<<gE, 256, 0, stream>>>(src, cursor, csr, e);
    k_sortcsr<<<gWave, 256, 0, stream>>>(dst, offs, csr, n);

    // layer 1 aggregation + fused layer-2 transform
    k_agg1<<<gWave, 256, 0, stream>>>(csr, offs, H, s1src, s1dst,
                                      Wout, aout, h2, s2src, s2dst, n);
    // layer 2 aggregation + elu + log_softmax
    k_agg2<<<gWave, 256, 0, stream>>>(csr, offs, h2, s2src, s2dst, out, n);
}

// Round 8
// 1310.654 us; speedup vs baseline: 1.0830x; 1.0830x over previous
//
#include <hip/hip_runtime.h>
#include <cstdint>
#include <cstddef>

#define ALPHA 0.2f

__device__ __forceinline__ float lrelu(float x) { return x > 0.f ? x : ALPHA * x; }

// round-to-nearest-even bf16 quantization, kept in f32
__device__ __forceinline__ float qbf(float x)
{
    uint32_t u = __float_as_uint(x);
    uint32_t r = (u + 0x7FFFu + ((u >> 16) & 1u)) & 0xFFFF0000u;
    return __uint_as_float(r);
}

__device__ __forceinline__ float readlane_f(float v, int l)
{
    return __int_as_float(__builtin_amdgcn_readlane(__float_as_int(v), l));
}

// ---------------------------------------------------------------------------
// GEMM1 + fused scores: H[n, h*64+o] = sum_k q(x[n,k]) * q(Wh[h,k,o]),
// s1src[n,h] = H row . q(a[h,:64]), s1dst[n,h] = H row . q(a[h,64:]).
// Tile 64 rows x 256 cols, BK=32, 256 threads, micro 4x16.
// ---------------------------------------------------------------------------
__global__ __launch_bounds__(256) void k_gemm1(const float* __restrict__ x,
                                               const float* __restrict__ Wh,
                                               const float* __restrict__ a,
                                               float* __restrict__ H,
                                               float* __restrict__ s1src,
                                               float* __restrict__ s1dst, int n)
{
    __shared__ float As[32][68];    // transposed A tile, padded
    __shared__ float Bs[32][256];
    __shared__ float Pa[64][17];    // per-(row,txgroup) partial dots (src)
    __shared__ float Pb[64][17];    // (dst)
    __shared__ float avs[256], avd[256];
    const int tid = threadIdx.x;
    const int row0 = blockIdx.x * 64;
    const int tx = tid & 15, ty = tid >> 4;

    // stage attention vectors (col-major over the 256 concat cols)
    {
        int h = tid >> 6, o = tid & 63;
        avs[tid] = qbf(a[h * 128 + o]);
        avd[tid] = qbf(a[h * 128 + 64 + o]);
    }

    float acc[4][16];
#pragma unroll
    for (int r = 0; r < 4; ++r)
#pragma unroll
        for (int c = 0; c < 16; ++c) acc[r][c] = 0.f;

    for (int k0 = 0; k0 < 256; k0 += 32) {
        for (int j = tid; j < 512; j += 256) {
            int r = j >> 3, kk = (j & 7) << 2;
            int gr = row0 + r; if (gr >= n) gr = n - 1;
            const float4 v = *(const float4*)&x[(size_t)gr * 256 + k0 + kk];
            As[kk + 0][r] = qbf(v.x); As[kk + 1][r] = qbf(v.y);
            As[kk + 2][r] = qbf(v.z); As[kk + 3][r] = qbf(v.w);
        }
        for (int j = tid; j < 2048; j += 256) {
            int kk = j >> 6, c4 = j & 63;
            int h = c4 >> 4, o = (c4 & 15) << 2;
            const float4 v = *(const float4*)&Wh[h * 16384 + (k0 + kk) * 64 + o];
            float* bp = &Bs[kk][c4 << 2];
            bp[0] = qbf(v.x); bp[1] = qbf(v.y); bp[2] = qbf(v.z); bp[3] = qbf(v.w);
        }
        __syncthreads();
#pragma unroll
        for (int kk = 0; kk < 32; ++kk) {
            const float4 av4 = *(const float4*)&As[kk][ty << 2];
            const float4 b0 = *(const float4*)&Bs[kk][tx * 16 + 0];
            const float4 b1 = *(const float4*)&Bs[kk][tx * 16 + 4];
            const float4 b2 = *(const float4*)&Bs[kk][tx * 16 + 8];
            const float4 b3 = *(const float4*)&Bs[kk][tx * 16 + 12];
            const float av[4]  = {av4.x, av4.y, av4.z, av4.w};
            const float bv[16] = {b0.x, b0.y, b0.z, b0.w, b1.x, b1.y, b1.z, b1.w,
                                  b2.x, b2.y, b2.z, b2.w, b3.x, b3.y, b3.z, b3.w};
#pragma unroll
            for (int r = 0; r < 4; ++r)
#pragma unroll
                for (int c = 0; c < 16; ++c) acc[r][c] += av[r] * bv[c];
        }
        __syncthreads();
    }
    // store H + stash score partials
#pragma unroll
    for (int r = 0; r < 4; ++r) {
        int row = (ty << 2) + r;
        int gr = row0 + row;
        float ps = 0.f, pd = 0.f;
#pragma unroll
        for (int c = 0; c < 16; ++c) {
            ps += acc[r][c] * avs[tx * 16 + c];
            pd += acc[r][c] * avd[tx * 16 + c];
        }
        Pa[row][tx] = ps;
        Pb[row][tx] = pd;
        if (gr < n) {
            float* dst = &H[(size_t)gr * 256 + tx * 16];
#pragma unroll
            for (int i = 0; i < 4; ++i)
                *(float4*)&dst[4 * i] = make_float4(acc[r][4 * i + 0], acc[r][4 * i + 1],
                                                    acc[r][4 * i + 2], acc[r][4 * i + 3]);
        }
    }
    __syncthreads();
    // reduce partials: 64 rows x 4 heads x {src,dst}
    for (int o = tid; o < 512; o += 256) {
        int row = o >> 3, h = (o >> 1) & 3, which = o & 1;
        const float* P = which ? &Pb[row][0] : &Pa[row][0];
        float s = P[h * 4 + 0] + P[h * 4 + 1] + P[h * 4 + 2] + P[h * 4 + 3];
        int gr = row0 + row;
        if (gr < n) {
            if (which) s1dst[gr * 4 + h] = s;
            else       s1src[gr * 4 + h] = s;
        }
    }
}

// ---------------------------------------------------------------------------
// CSR build (scatter stores EDGE IDs; buckets sorted by edge id)
// ---------------------------------------------------------------------------
__global__ void k_zero(int* __restrict__ p, int n)
{
    int i = blockIdx.x * 256 + threadIdx.x;
    if (i < n) p[i] = 0;
}

__global__ void k_hist(const int* __restrict__ src, int* __restrict__ counts, int e)
{
    int i = blockIdx.x * 256 + threadIdx.x;
    if (i < e) atomicAdd(&counts[src[i]], 1);
}

__global__ __launch_bounds__(256) void k_blocksum(const int* __restrict__ counts,
                                                  int* __restrict__ bsum, int n)
{
    int tid = threadIdx.x;
    int i0 = blockIdx.x * 2048 + tid * 8;
    int s = 0;
#pragma unroll
    for (int k = 0; k < 8; ++k) {
        int i = i0 + k;
        if (i < n) s += counts[i];
    }
#pragma unroll
    for (int m = 32; m >= 1; m >>= 1) s += __shfl_xor(s, m);
    __shared__ int ws[4];
    int lane = tid & 63, wv = tid >> 6;
    if (lane == 0) ws[wv] = s;
    __syncthreads();
    if (tid == 0) bsum[blockIdx.x] = ws[0] + ws[1] + ws[2] + ws[3];
}

__global__ void k_scanmeta(const int* __restrict__ bsum, int* __restrict__ choff, int nchunk)
{
    int lane = threadIdx.x;   // 64 threads, nchunk <= 64
    int v = (lane < nchunk) ? bsum[lane] : 0;
    int incl = v;
#pragma unroll
    for (int d = 1; d < 64; d <<= 1) {
        int t = __shfl_up(incl, d);
        if (lane >= d) incl += t;
    }
    if (lane < nchunk) choff[lane] = incl - v;
}

__global__ __launch_bounds__(256) void k_apply(const int* __restrict__ counts,
                                               const int* __restrict__ choff,
                                               int* __restrict__ offsets,
                                               int* __restrict__ cursor, int n)
{
    int tid = threadIdx.x;
    int i0 = blockIdx.x * 2048 + tid * 8;
    int c[8]; int s = 0;
#pragma unroll
    for (int k = 0; k < 8; ++k) {
        int i = i0 + k;
        c[k] = (i < n) ? counts[i] : 0;
        s += c[k];
    }
    int lane = tid & 63, wv = tid >> 6;
    int incl = s;
#pragma unroll
    for (int d = 1; d < 64; d <<= 1) {
        int t = __shfl_up(incl, d);
        if (lane >= d) incl += t;
    }
    __shared__ int ws[4];
    if (lane == 63) ws[wv] = incl;
    __syncthreads();
    int woff = 0;
    for (int w = 0; w < 4; ++w)
        if (w < wv) woff += ws[w];
    int run = incl - s + woff + choff[blockIdx.x];
#pragma unroll
    for (int k = 0; k < 8; ++k) {
        int i = i0 + k;
        if (i < n) { offsets[i] = run; cursor[i] = run; }
        run += c[k];
        if (i == n - 1) offsets[n] = run;
    }
}

__global__ void k_scatter(const int* __restrict__ src,
                          int* __restrict__ cursor, int* __restrict__ csr, int e)
{
    int i = blockIdx.x * 256 + threadIdx.x;
    if (i < e) {
        int pos = atomicAdd(&cursor[src[i]], 1);
        csr[pos] = i;                    // edge id (unique key)
    }
}

// sort each bucket's edge ids ascending (deterministic order == np order)
__global__ __launch_bounds__(256) void k_sortcsr(const int* __restrict__ offsets,
                                                 int* __restrict__ csr, int n)
{
    int gtid = blockIdx.x * 256 + threadIdx.x;
    int node = gtid >> 6, lane = gtid & 63;
    if (node >= n) return;
    int beg = offsets[node], end = offsets[node + 1];
    int cnt = end - beg;
    if (cnt <= 0) return;
    if (cnt <= 64) {
        int v = (lane < cnt) ? csr[beg + lane] : 0x7FFFFFFF;
#pragma unroll
        for (int k = 2; k <= 64; k <<= 1) {
#pragma unroll
            for (int j = k >> 1; j > 0; j >>= 1) {
                int o = __shfl_xor(v, j);
                bool up    = ((lane & k) == 0);
                bool lower = ((lane & j) == 0);
                int mn = min(v, o), mx = max(v, o);
                v = (lower == up) ? mn : mx;
            }
        }
        if (lane < cnt) csr[beg + lane] = v;
    } else {
        if (lane == 0) {    // cold path: degree > 64 (essentially never at E/N=16)
            for (int i = beg + 1; i < end; ++i) {
                int key = csr[i]; int j = i - 1;
                while (j >= beg && csr[j] > key) { csr[j + 1] = csr[j]; --j; }
                csr[j + 1] = key;
            }
        }
    }
}

// ---------------------------------------------------------------------------
// w1 + csrd: slot-parallel layer-1 edge weights (4 heads) from sorted eids
// ---------------------------------------------------------------------------
__global__ void k_w1(const int* __restrict__ csr_eid,
                     const int* __restrict__ src, const int* __restrict__ dst,
                     const float* __restrict__ s1src, const float* __restrict__ s1dst,
                     int* __restrict__ csrd, float* __restrict__ w1, int e)
{
    int i = blockIdx.x * 256 + threadIdx.x;
    if (i >= e) return;
    int eid = csr_eid[i];
    int s = src[eid], d = dst[eid];
    csrd[i] = d;
    const float4 aa = *(const float4*)&s1src[(size_t)s * 4];
    const float4 bb = *(const float4*)&s1dst[(size_t)d * 4];
    float4 w;
    w.x = expf(-lrelu(aa.x + bb.x));
    w.y = expf(-lrelu(aa.y + bb.y));
    w.z = expf(-lrelu(aa.z + bb.z));
    w.w = expf(-lrelu(aa.w + bb.w));
    *(float4*)&w1[(size_t)i * 4] = w;
}

// layer-2 edge weights (after agg1 produces s2)
__global__ void k_w2(const int* __restrict__ csr_eid,
                     const int* __restrict__ src, const int* __restrict__ dst,
                     const float* __restrict__ s2src, const float* __restrict__ s2dst,
                     float* __restrict__ w2, int e)
{
    int i = blockIdx.x * 256 + threadIdx.x;
    if (i >= e) return;
    int eid = csr_eid[i];
    float z = s2src[src[eid]] + s2dst[dst[eid]];
    w2[i] = expf(-lrelu(z));
}

// ---------------------------------------------------------------------------
// agg1 (fused with GEMM2): per-node wave; precomputed weights; 2-deep
// pipelined H-row gather; strictly sequential edge order.
// ---------------------------------------------------------------------------
__global__ __launch_bounds__(256) void k_agg1(const int* __restrict__ csrd,
                                              const int* __restrict__ offsets,
                                              const float* __restrict__ H,
                                              const float* __restrict__ w1,
                                              const float* __restrict__ Wout,
                                              const float* __restrict__ aout,
                                              float* __restrict__ h2,
                                              float* __restrict__ s2src,
                                              float* __restrict__ s2dst, int n)
{
    __shared__ float Wt[32][256];   // Wt[c][k] = q(Wout[k,c])
    const int tid = threadIdx.x;
    for (int j = tid; j < 8192; j += 256) {   // conflict-free writes (k contiguous)
        int c = j >> 8, k = j & 255;
        Wt[c][k] = qbf(Wout[k * 32 + c]);
    }
    __syncthreads();

    int gtid = blockIdx.x * 256 + tid;
    int node = gtid >> 6, lane = gtid & 63;
    if (node >= n) return;
    const int beg = offsets[node], end = offsets[node + 1];
    const int wsel = lane & 48;
    float ax = 0.f, ay = 0.f, az = 0.f, aw = 0.f, wsum = 0.f;
    for (int j = beg; j < end; j += 16) {
        int slot = j + (lane & 15);
        bool okl = slot < end;
        int dv   = okl ? csrd[slot] : 0;
        float wv = okl ? w1[(size_t)slot * 4 + (lane >> 4)] : 0.f;
        int cnt = min(16, end - j);
        // 2-deep pipeline: issue load t+1 before consuming t
        int d = __builtin_amdgcn_readlane(dv, 0);
        float4 hv = *(const float4*)&H[(size_t)d * 256 + lane * 4];
        int t = 0;
        for (; t + 1 < cnt; ++t) {
            int d2 = __builtin_amdgcn_readlane(dv, t + 1);
            float4 hv2 = *(const float4*)&H[(size_t)d2 * 256 + lane * 4];
            float w = __shfl(wv, wsel + t);
            ax += w * hv.x; ay += w * hv.y; az += w * hv.z; aw += w * hv.w;
            wsum += w;
            hv = hv2;
        }
        float w = __shfl(wv, wsel + t);
        ax += w * hv.x; ay += w * hv.y; az += w * hv.z; aw += w * hv.w;
        wsum += w;
    }
    float inv = 1.f / wsum;
    float r0 = ax * inv, r1 = ay * inv, r2 = az * inv, r3 = aw * inv;
    r0 = r0 > 0.f ? r0 : expm1f(r0);   // elu -> x1 cols 4L..4L+3
    r1 = r1 > 0.f ? r1 : expm1f(r1);
    r2 = r2 > 0.f ? r2 : expm1f(r2);
    r3 = r3 > 0.f ? r3 : expm1f(r3);

    // fused GEMM2: partial h2[c] over this lane's 4 k's, wave tree-reduce
    float p[32];
#pragma unroll
    for (int c = 0; c < 32; ++c) {
        const float4 wv4 = *(const float4*)&Wt[c][lane << 2];
        p[c] = r0 * wv4.x + r1 * wv4.y + r2 * wv4.z + r3 * wv4.w;
    }
#pragma unroll
    for (int m = 32; m >= 1; m >>= 1) {
#pragma unroll
        for (int c = 0; c < 32; ++c) p[c] += __shfl_xor(p[c], m);
    }
    if (lane == 0) {
        float ss = 0.f, sd2 = 0.f;
#pragma unroll
        for (int c = 0; c < 32; ++c) {
            ss  += p[c] * qbf(aout[c]);
            sd2 += p[c] * qbf(aout[32 + c]);
        }
        float* dst = &h2[(size_t)node * 32];
#pragma unroll
        for (int i = 0; i < 8; ++i)
            *(float4*)&dst[4 * i] = make_float4(p[4 * i + 0], p[4 * i + 1],
                                                p[4 * i + 2], p[4 * i + 3]);
        s2src[node] = ss;
        s2dst[node] = sd2;
    }
}

// ---------------------------------------------------------------------------
// agg2 + elu + log_softmax -> out. One wave per node; lane=class (dup x2);
// precomputed w2; LDS-free readlane broadcasts; sequential edge order.
// ---------------------------------------------------------------------------
__global__ __launch_bounds__(256) void k_agg2(const int* __restrict__ csrd,
                                              const int* __restrict__ offsets,
                                              const float* __restrict__ h2,
                                              const float* __restrict__ w2,
                                              float* __restrict__ out, int n)
{
    int gtid = blockIdx.x * 256 + threadIdx.x;
    int node = gtid >> 6, lane = gtid & 63;
    if (node >= n) return;
    int c = lane & 31;
    int beg = offsets[node], end = offsets[node + 1];
    float acc = 0.f, wsum = 0.f;
    for (int j = beg; j < end; j += 64) {
        int slot = j + lane;
        bool okl = slot < end;
        int dv    = okl ? csrd[slot] : 0;
        float wvv = okl ? w2[slot] : 0.f;
        int cnt = min(64, end - j);
        int d = __builtin_amdgcn_readlane(dv, 0);
        float hv = h2[(size_t)d * 32 + c];
        int t = 0;
        for (; t + 1 < cnt; ++t) {
            int d2 = __builtin_amdgcn_readlane(dv, t + 1);
            float hv2 = h2[(size_t)d2 * 32 + c];
            float w = readlane_f(wvv, t);
            acc += w * hv; wsum += w;
            hv = hv2;
        }
        float w = readlane_f(wvv, t);
        acc += w * hv; wsum += w;
    }
    float v = acc / wsum;
    v = v > 0.f ? v : expm1f(v);          // elu
    float m = v;
#pragma unroll
    for (int i = 16; i >= 1; i >>= 1) m = fmaxf(m, __shfl_xor(m, i));
    float ex = expf(v - m);
    float se = ex;
#pragma unroll
    for (int i = 16; i >= 1; i >>= 1) se += __shfl_xor(se, i);
    float r = v - m - logf(se);
    if (lane < 32) out[(size_t)node * 32 + c] = r;
}

// ---------------------------------------------------------------------------
extern "C" void kernel_launch(void* const* d_in, const int* in_sizes, int n_in,
                              void* d_out, int out_size, void* d_ws, size_t ws_size,
                              hipStream_t stream)
{
    const float* x    = (const float*)d_in[0];
    const int*   ei   = (const int*)d_in[1];
    const float* Wh   = (const float*)d_in[2];
    const float* ah   = (const float*)d_in[3];
    const float* Wout = (const float*)d_in[4];
    const float* aout = (const float*)d_in[5];
    float* out = (float*)d_out;

    const int n = in_sizes[0] / 256;
    const int e = in_sizes[1] / 2;
    const int* src = ei;
    const int* dst = ei + e;

    auto align = [](size_t v) { return (v + 255) & ~(size_t)255; };
    char* w = (char*)d_ws;
    float* H      = (float*)w; w += align((size_t)n * 256 * 4);   // 102.4 MB
    float* h2     = (float*)w; w += align((size_t)n * 32 * 4);    //  12.8 MB
    int*   csr    = (int*)w;   w += align((size_t)e * 4);         //   6.4 MB (edge ids)
    int*   csrd   = (int*)w;   w += align((size_t)e * 4);         //   6.4 MB (dst ids)
    float* w1     = (float*)w; w += align((size_t)e * 4 * 4);     //  25.6 MB
    float* w2     = (float*)w; w += align((size_t)e * 4);         //   6.4 MB
    float* s1src  = (float*)w; w += align((size_t)n * 4 * 4);
    float* s1dst  = (float*)w; w += align((size_t)n * 4 * 4);
    int*   counts = (int*)w;   w += align((size_t)n * 4);
    int*   offs   = (int*)w;   w += align((size_t)(n + 1) * 4);
    int*   cursor = (int*)w;   w += align((size_t)n * 4);
    float* s2src  = (float*)w; w += align((size_t)n * 4);
    float* s2dst  = (float*)w; w += align((size_t)n * 4);
    int*   bsum   = (int*)w;   w += align(4096);
    int*   choff  = (int*)w;   w += align(4096);

    const int nchunk = (n + 2047) / 2048;
    const int gN256  = (n + 255) / 256;
    const int gWave  = (n + 3) / 4;      // 4 node-waves per 256-thread block
    const int gE     = (e + 255) / 256;

    // layer 1 feature transform (+ fused attention scores)
    k_gemm1<<<(n + 63) / 64, 256, 0, stream>>>(x, Wh, ah, H, s1src, s1dst, n);

    // deterministic CSR by src (sorted edge-id buckets)
    k_zero<<<gN256, 256, 0, stream>>>(counts, n);
    k_hist<<<gE, 256, 0, stream>>>(src, counts, e);
    k_blocksum<<<nchunk, 256, 0, stream>>>(counts, bsum, n);
    k_scanmeta<<<1, 64, 0, stream>>>(bsum, choff, nchunk);
    k_apply<<<nchunk, 256, 0, stream>>>(counts, choff, offs, cursor, n);
    k_scatter<<<gE, 256, 0, stream>>>(src, cursor, csr, e);
    k_sortcsr<<<gWave, 256, 0, stream>>>(offs, csr, n);

    // edge weights layer 1 (+ dst ids in csr order)
    k_w1<<<gE, 256, 0, stream>>>(csr, src, dst, s1src, s1dst, csrd, w1, e);

    // layer 1 aggregation + fused layer-2 transform
    k_agg1<<<gWave, 256, 0, stream>>>(csrd, offs, H, w1, Wout, aout,
                                      h2, s2src, s2dst, n);
    // edge weights layer 2
    k_w2<<<gE, 256, 0, stream>>>(csr, src, dst, s2src, s2dst, w2, e);

    // layer 2 aggregation + elu + log_softmax
    k_agg2<<<gWave, 256, 0, stream>>>(csrd, offs, h2, w2, out, n);
}